// Round 2
// baseline (137.801 us; speedup 1.0000x reference)
//
#include <hip/hip_runtime.h>
#include <math.h>

#define N_SAMPLES 8192
#define DIM 128
#define NCLS 1024
#define MARGIN_V 0.3f

using bf16x8  = __attribute__((ext_vector_type(8)))  short;
using f32x16  = __attribute__((ext_vector_type(16))) float;
using short8  = __attribute__((ext_vector_type(8)))  short;

// ---- monotonic float<->uint encoding for atomic max/min on floats ----
__device__ __forceinline__ unsigned enc_f(float f) {
  unsigned b = __float_as_uint(f);
  return (b & 0x80000000u) ? ~b : (b | 0x80000000u);
}
__device__ __forceinline__ float dec_f(unsigned u) {
  unsigned b = (u & 0x80000000u) ? (u & 0x7FFFFFFFu) : ~u;
  return __uint_as_float(b);
}

__device__ __forceinline__ short bf16_rne(float x) {
  unsigned u = __float_as_uint(x);
  unsigned r = u + 0x7FFFu + ((u >> 16) & 1u);
  return (short)(r >> 16);
}
__device__ __forceinline__ float bf16_tof(short h) {
  return __uint_as_float(((unsigned)(unsigned short)h) << 16);
}

// Packed fragment layout (both operands, row-major source [row][k=0..127]):
//   tile = row>>5, kstep = oct>>1 (oct = k/8), lane = ((oct&1)<<5)|(row&31)
//   element index (in short8 units) = ((tile*8 + kstep)*2 + plane)*64 + lane
// plane 0 = hi bf16, plane 1 = lo bf16. Matches mfma_32x32x16 A/B operand
// layout: operand[row=lane&31][k=(lane>>5)*8+j].

// K1: zero centersum+counts, init dp/dn sentinels (grid-stride)
__global__ void init_kernel(float* centersum, int* counts, unsigned* dpbits, unsigned* dnbits) {
  int i = blockIdx.x * 256 + threadIdx.x;
  if (i < NCLS * DIM) centersum[i] = 0.f;
  if (i < NCLS) {
    counts[i] = 0;
    dpbits[i] = enc_f(-INFINITY);
    dnbits[i] = enc_f(INFINITY);
  }
}

// K2: per (row, oct): x2 partial + reduce, counts atomic, centersum atomicAdd,
// pack inputs -> Bpk (hi/lo fragment planes)
__global__ __launch_bounds__(256) void accum_pack_kernel(
    const float* __restrict__ inputs, const int* __restrict__ targets,
    float* __restrict__ x2, int* counts, float* centersum, short8* __restrict__ Bpk) {
  int gid = blockIdx.x * 256 + threadIdx.x;
  int row = gid >> 4;
  int oct = gid & 15;
  const float4* p = (const float4*)(inputs + (size_t)row * DIM + oct * 8);
  float4 v0 = p[0], v1 = p[1];
  float v[8] = {v0.x, v0.y, v0.z, v0.w, v1.x, v1.y, v1.z, v1.w};

  // x2 partial + 16-lane reduce
  float s = 0.f;
  #pragma unroll
  for (int i = 0; i < 8; i++) s += v[i] * v[i];
  #pragma unroll
  for (int m = 1; m < 16; m <<= 1) s += __shfl_xor(s, m);

  int t = targets[row];
  if (oct == 0) {
    x2[row] = s;
    atomicAdd(&counts[t], 1);
  }
  // scatter-add into class center sum
  #pragma unroll
  for (int i = 0; i < 8; i++) atomicAdd(&centersum[t * DIM + oct * 8 + i], v[i]);

  // pack hi/lo
  short8 hi, lo;
  #pragma unroll
  for (int i = 0; i < 8; i++) {
    short h = bf16_rne(v[i]);
    hi[i] = h;
    lo[i] = bf16_rne(v[i] - bf16_tof(h));
  }
  int tile = row >> 5, ks = oct >> 1, lane = ((oct & 1) << 5) | (row & 31);
  size_t fi = (size_t)((tile * 8 + ks) * 2) * 64 + lane;
  Bpk[fi] = hi;
  Bpk[fi + 64] = lo;
}

// K3: normalize centers, c2, pack centers -> Apk
__global__ __launch_bounds__(256) void centers_pack_kernel(
    const float* __restrict__ centersum, const int* __restrict__ counts,
    float* __restrict__ c2, short8* __restrict__ Apk) {
  int gid = blockIdx.x * 256 + threadIdx.x;
  int c = gid >> 4;
  int oct = gid & 15;
  int cnt = counts[c];
  float inv = (cnt > 0) ? 1.f / (float)cnt : 0.f;
  float v[8];
  float s = 0.f;
  #pragma unroll
  for (int i = 0; i < 8; i++) {
    v[i] = centersum[c * DIM + oct * 8 + i] * inv;
    s += v[i] * v[i];
  }
  #pragma unroll
  for (int m = 1; m < 16; m <<= 1) s += __shfl_xor(s, m);
  if (oct == 0) c2[c] = s;

  short8 hi, lo;
  #pragma unroll
  for (int i = 0; i < 8; i++) {
    short h = bf16_rne(v[i]);
    hi[i] = h;
    lo[i] = bf16_rne(v[i] - bf16_tof(h));
  }
  int tile = c >> 5, ks = oct >> 1, lane = ((oct & 1) << 5) | (c & 31);
  size_t fi = (size_t)((tile * 8 + ks) * 2) * 64 + lane;
  Apk[fi] = hi;
  Apk[fi + 64] = lo;
}

// K4: MFMA dist. Block tile 128 classes x 128 samples; 4 waves, each 64x64
// (2x2 of 32x32x16 tiles). Split-bf16: acc += Ahi*Bhi + Ahi*Blo + Alo*Bhi.
// Fragments load directly from packed global (L2-resident), no LDS staging.
__global__ __launch_bounds__(256) void dist_kernel(
    const short8* __restrict__ Apk, const short8* __restrict__ Bpk,
    const float* __restrict__ x2, const float* __restrict__ c2,
    const int* __restrict__ targets, unsigned* dpbits, unsigned* dnbits) {
  __shared__ float sc2[128];
  __shared__ float sx2[128];
  __shared__ int stgt[128];

  int tid = threadIdx.x;
  int jbase = blockIdx.x * 128;
  int cbase = blockIdx.y * 128;
  int wave = tid >> 6, lane = tid & 63;
  int wm = wave >> 1, wn = wave & 1;

  if (tid < 128) {
    sc2[tid] = c2[cbase + tid];
    sx2[tid] = x2[jbase + tid];
    stgt[tid] = targets[jbase + tid];
  }

  f32x16 acc[2][2];
  #pragma unroll
  for (int i = 0; i < 2; i++)
    #pragma unroll
    for (int j = 0; j < 2; j++)
      acc[i][j] = (f32x16)(0.f);

  int mtg0 = (cbase >> 5) + wm * 2;  // global m-tile of mt=0
  int ntg0 = (jbase >> 5) + wn * 2;

  #pragma unroll 2
  for (int ks = 0; ks < 8; ks++) {
    bf16x8 a[2][2], b[2][2];  // [tile][plane]
    #pragma unroll
    for (int mt = 0; mt < 2; mt++) {
      size_t base = (size_t)(((mtg0 + mt) * 8 + ks) * 2) * 64 + lane;
      a[mt][0] = Apk[base];
      a[mt][1] = Apk[base + 64];
    }
    #pragma unroll
    for (int nt = 0; nt < 2; nt++) {
      size_t base = (size_t)(((ntg0 + nt) * 8 + ks) * 2) * 64 + lane;
      b[nt][0] = Bpk[base];
      b[nt][1] = Bpk[base + 64];
    }
    #pragma unroll
    for (int mt = 0; mt < 2; mt++)
      #pragma unroll
      for (int nt = 0; nt < 2; nt++) {
        acc[mt][nt] = __builtin_amdgcn_mfma_f32_32x32x16_bf16(a[mt][0], b[nt][0], acc[mt][nt], 0, 0, 0);
        acc[mt][nt] = __builtin_amdgcn_mfma_f32_32x32x16_bf16(a[mt][0], b[nt][1], acc[mt][nt], 0, 0, 0);
        acc[mt][nt] = __builtin_amdgcn_mfma_f32_32x32x16_bf16(a[mt][1], b[nt][0], acc[mt][nt], 0, 0, 0);
      }
  }

  __syncthreads();  // LDS staging visible to all

  // epilogue: dist2 = c2 + x2 - 2*dot; masked max/min; reduce over 32 cols
  int half = lane >> 5;
  int col = lane & 31;
  #pragma unroll
  for (int mt = 0; mt < 2; mt++) {
    #pragma unroll
    for (int r = 0; r < 16; r++) {
      int rowl = (r & 3) + 8 * (r >> 2) + 4 * half;
      int c_loc = wm * 64 + mt * 32 + rowl;
      int cg = cbase + c_loc;
      float c2v = sc2[c_loc];
      float pmax = -INFINITY, nmin = INFINITY;
      #pragma unroll
      for (int nt = 0; nt < 2; nt++) {
        int j_loc = wn * 64 + nt * 32 + col;
        float d2 = c2v + sx2[j_loc] - 2.f * acc[mt][nt][r];
        if (stgt[j_loc] == cg) pmax = fmaxf(pmax, d2);
        else                   nmin = fminf(nmin, d2);
      }
      #pragma unroll
      for (int m = 1; m < 32; m <<= 1) {
        pmax = fmaxf(pmax, __shfl_xor(pmax, m));
        nmin = fminf(nmin, __shfl_xor(nmin, m));
      }
      if (col == 0) {
        atomicMax(&dpbits[cg], enc_f(pmax));
        atomicMin(&dnbits[cg], enc_f(nmin));
      }
    }
  }
}

// K5: weighted reduce over classes -> loss, prec
__global__ void finalize_kernel(const unsigned* __restrict__ dpbits, const unsigned* __restrict__ dnbits,
                                const int* __restrict__ counts, float* __restrict__ out) {
  int t = threadIdx.x;  // 256
  float ls = 0.f, ps = 0.f;
  for (int c = t; c < NCLS; c += 256) {
    int cnt = counts[c];
    if (cnt > 0) {
      float dp = dec_f(dpbits[c]);
      float dn = dec_f(dnbits[c]);
      ls += (float)cnt * fmaxf(dp - dn + MARGIN_V, 0.f);
      ps += (float)cnt * ((dn > dp) ? 1.f : 0.f);
    }
  }
  #pragma unroll
  for (int sh = 32; sh > 0; sh >>= 1) {
    ls += __shfl_down(ls, sh);
    ps += __shfl_down(ps, sh);
  }
  __shared__ float sl[4], sp[4];
  int wave = t >> 6, lane = t & 63;
  if (lane == 0) { sl[wave] = ls; sp[wave] = ps; }
  __syncthreads();
  if (t == 0) {
    out[0] = (sl[0] + sl[1] + sl[2] + sl[3]) / (float)N_SAMPLES;
    out[1] = (sp[0] + sp[1] + sp[2] + sp[3]) / (float)N_SAMPLES;
  }
}

extern "C" void kernel_launch(void* const* d_in, const int* in_sizes, int n_in,
                              void* d_out, int out_size, void* d_ws, size_t ws_size,
                              hipStream_t stream) {
  const float* inputs = (const float*)d_in[0];
  const int* targets = (const int*)d_in[1];
  float* out = (float*)d_out;

  char* w = (char*)d_ws;
  float* centersum = (float*)w;     w += (size_t)NCLS * DIM * 4;       // 512 KB
  float* x2 = (float*)w;            w += (size_t)N_SAMPLES * 4;        // 32 KB
  float* c2 = (float*)w;            w += (size_t)NCLS * 4;             // 4 KB
  int* counts = (int*)w;            w += (size_t)NCLS * 4;             // 4 KB
  unsigned* dpbits = (unsigned*)w;  w += (size_t)NCLS * 4;             // 4 KB
  unsigned* dnbits = (unsigned*)w;  w += (size_t)NCLS * 4;             // 4 KB
  short8* Apk = (short8*)w;         w += (size_t)NCLS * DIM * 2 * 2;   // 512 KB (hi+lo)
  short8* Bpk = (short8*)w;         w += (size_t)N_SAMPLES * DIM * 2 * 2;  // 4 MB

  init_kernel<<<(NCLS * DIM + 255) / 256, 256, 0, stream>>>(centersum, counts, dpbits, dnbits);
  accum_pack_kernel<<<N_SAMPLES * 16 / 256, 256, 0, stream>>>(inputs, targets, x2, counts, centersum, Bpk);
  centers_pack_kernel<<<NCLS * 16 / 256, 256, 0, stream>>>(centersum, counts, c2, Apk);
  dist_kernel<<<dim3(N_SAMPLES / 128, NCLS / 128), 256, 0, stream>>>(
      Apk, Bpk, x2, c2, targets, dpbits, dnbits);
  finalize_kernel<<<1, 256, 0, stream>>>(dpbits, dnbits, counts, out);
}